// Round 12
// baseline (199.804 us; speedup 1.0000x reference)
//
#include <hip/hip_runtime.h>
#include <math.h>

// Problem constants
#define BATCH 4
#define SEQ   2048
#define HDIM  128
#define NHEAD 8
#define MROWS (BATCH*SEQ)    // 8192
#define QKVN  (3*NHEAD*HDIM) // 3072
#define YN    (NHEAD*HDIM)   // 1024
#define NROWS 65536          // 32 heads * 2048 rows

#define CS 0.12751744f   // (1/sqrt(128)) * log2(e)

using bfrag = __attribute__((ext_vector_type(8))) short;  // 8 bf16 (4 VGPRs)
using f32x4 = __attribute__((ext_vector_type(4))) float;
using s16x4 = __attribute__((ext_vector_type(4))) short;

__device__ __forceinline__ f32x4 mfma16(bfrag a, bfrag b, f32x4 c) {
    return __builtin_amdgcn_mfma_f32_16x16x32_bf16(a, b, c, 0, 0, 0);
}
__device__ __forceinline__ short f2bf(float f) {
    union { float f; unsigned u; } v; v.f = f;
    unsigned r = v.u + 0x7FFFu + ((v.u >> 16) & 1u);  // RNE
    return (short)(r >> 16);
}
__device__ __forceinline__ float bf2f(short s) {
    union { unsigned u; float f; } v; v.u = ((unsigned)(unsigned short)s) << 16;
    return v.f;
}
__device__ __forceinline__ unsigned cvtpk(float lo, float hi) {
    unsigned r;
    asm("v_cvt_pk_bf16_f32 %0, %1, %2" : "=v"(r) : "v"(lo), "v"(hi));
    return r;
}
__device__ __forceinline__ void perm32swap(unsigned &x, unsigned &y) {
    asm volatile("v_permlane32_swap_b32 %0, %1" : "+v"(x), "+v"(y));
}
__device__ __forceinline__ f32x4 z4() { f32x4 z; z[0]=0.f; z[1]=0.f; z[2]=0.f; z[3]=0.f; return z; }

// In-register P redistribution (C-layout -> A-frag layout), validated in attn8.
__device__ __forceinline__ void redist(const float p[4][4], bool hi16,
                                       bfrag &pa0o, bfrag &pa1o) {
    unsigned pk0[2], pk1[2], pk2[2], pk3[2];
    pk0[0] = cvtpk(p[0][0], p[0][1]); pk0[1] = cvtpk(p[0][2], p[0][3]);
    pk1[0] = cvtpk(p[1][0], p[1][1]); pk1[1] = cvtpk(p[1][2], p[1][3]);
    pk2[0] = cvtpk(p[2][0], p[2][1]); pk2[1] = cvtpk(p[2][2], p[2][3]);
    pk3[0] = cvtpk(p[3][0], p[3][1]); pk3[1] = cvtpk(p[3][2], p[3][3]);
    uint4 w0, w1;
    {
        unsigned A = pk0[0], C = pk1[0];
        perm32swap(A, C);
        unsigned A16 = __shfl_xor((int)A, 16), C16 = __shfl_xor((int)C, 16);
        w0.x = hi16 ? C16 : A;
        w0.z = hi16 ? C   : A16;
        unsigned B = pk0[1], D = pk1[1];
        perm32swap(B, D);
        unsigned B16 = __shfl_xor((int)B, 16), D16 = __shfl_xor((int)D, 16);
        w0.y = hi16 ? D16 : B;
        w0.w = hi16 ? D   : B16;
    }
    {
        unsigned E = pk2[0], G = pk3[0];
        perm32swap(E, G);
        unsigned E16 = __shfl_xor((int)E, 16), G16 = __shfl_xor((int)G, 16);
        w1.x = hi16 ? G16 : E;
        w1.z = hi16 ? G   : E16;
        unsigned F = pk2[1], H = pk3[1];
        perm32swap(F, H);
        unsigned F16 = __shfl_xor((int)F, 16), H16 = __shfl_xor((int)H, 16);
        w1.y = hi16 ? H16 : F;
        w1.w = hi16 ? H   : F16;
    }
    union { uint4 u; bfrag f; } cv0, cv1;
    cv0.u = w0; cv1.u = w1;
    pa0o = cv0.f; pa1o = cv1.f;
}

// ---------------------------------------------------------------------------
// Converters
// ---------------------------------------------------------------------------
__global__ __launch_bounds__(256) void conv_x(const float* __restrict__ x, short* __restrict__ XB) {
    int i = (blockIdx.x * 256 + threadIdx.x) * 4;
    float4 v = *(const float4*)(x + i);
    s16x4 o; o[0] = f2bf(v.x); o[1] = f2bf(v.y); o[2] = f2bf(v.z); o[3] = f2bf(v.w);
    *(s16x4*)(XB + i) = o;
}
__global__ __launch_bounds__(256) void conv_qkvT(const float* __restrict__ q, short* __restrict__ qT) {
    int t = blockIdx.x * 256 + threadIdx.x;         // 3072*128
    int n = t >> 7, k = t & 127;
    qT[t] = f2bf(q[(size_t)k * QKVN + n]);
}
__global__ __launch_bounds__(256) void conv_projT(const float* __restrict__ p, short* __restrict__ pT) {
    int t = blockIdx.x * 256 + threadIdx.x;         // 128*1024
    int h = t >> 10, r = t & 1023;
    pT[t] = f2bf(p[(size_t)r * HDIM + h]);
}

// ---------------------------------------------------------------------------
// GEMM1: x @ qkv scattered into per-head Qh/Kh/Vh[(b*8+n)*2048 + s2][h]
// ---------------------------------------------------------------------------
__global__ __launch_bounds__(256) void gemm_qkv(
    const short* __restrict__ XB, const short* __restrict__ qkvT,
    short* __restrict__ Qh, short* __restrict__ Kh, short* __restrict__ Vh)
{
    const int t = threadIdx.x, lane = t & 63, w = t >> 6;
    const int lr = lane & 15, lg = lane >> 4;
    const int m0 = blockIdx.x * 128 + (w >> 1) * 64;
    const int n0 = blockIdx.y * 128 + (w & 1) * 64;

    f32x4 acc[4][4];
    #pragma unroll
    for (int i = 0; i < 4; ++i)
        #pragma unroll
        for (int j = 0; j < 4; ++j) acc[i][j] = z4();

    #pragma unroll
    for (int c = 0; c < 4; ++c) {
        bfrag a[4], bb[4];
        #pragma unroll
        for (int rt = 0; rt < 4; ++rt)
            a[rt] = *(const bfrag*)(XB + (size_t)(m0 + rt * 16 + lr) * 128 + c * 32 + lg * 8);
        #pragma unroll
        for (int nt = 0; nt < 4; ++nt)
            bb[nt] = *(const bfrag*)(qkvT + (size_t)(n0 + nt * 16 + lr) * 128 + c * 32 + lg * 8);
        #pragma unroll
        for (int rt = 0; rt < 4; ++rt)
            #pragma unroll
            for (int nt = 0; nt < 4; ++nt)
                acc[rt][nt] = mfma16(a[rt], bb[nt], acc[rt][nt]);
    }

    const int part = blockIdx.y >> 3, c8 = blockIdx.y & 7;
    short* dst = (part == 0) ? Qh : ((part == 1) ? Kh : Vh);
    #pragma unroll
    for (int rt = 0; rt < 4; ++rt)
        #pragma unroll
        for (int j = 0; j < 4; ++j) {
            int r = m0 + rt * 16 + lg * 4 + j;
            int b = r >> 11, sl = r & 2047;
            int n = sl >> 8, s2 = (sl & 255) * 8 + c8;
            size_t rowbase = ((size_t)((b * 8 + n) * 2048 + s2)) * 128;
            #pragma unroll
            for (int nt = 0; nt < 4; ++nt) {
                int h = (w & 1) * 64 + nt * 16 + lr;
                dst[rowbase + h] = f2bf(acc[rt][nt][j]);
            }
        }
}

// ---------------------------------------------------------------------------
// Transpose V per head: Vh[bn][s2][d] -> Vt[bn][d][s2].
// ---------------------------------------------------------------------------
__global__ __launch_bounds__(256) void transp_v(
    const short* __restrict__ Vh, short* __restrict__ Vt)
{
    __shared__ short Ls[64][72];
    const int bn = blockIdx.z, s20 = blockIdx.x * 64, d0 = blockIdx.y * 64;
    const int t = threadIdx.x;
    const short* src = Vh + ((size_t)bn * SEQ + s20) * 128 + d0;
    {
        int r = t >> 2, ch = (t & 3) * 16;
        *(int4*)&Ls[r][ch]     = *(const int4*)(src + (size_t)r * 128 + ch);
        *(int4*)&Ls[r][ch + 8] = *(const int4*)(src + (size_t)r * 128 + ch + 8);
    }
    __syncthreads();
    {
        int dr = t >> 2, ch = (t & 3) * 16;
        short tmp[16];
        #pragma unroll
        for (int i = 0; i < 16; ++i) tmp[i] = Ls[ch + i][dr];
        short* dp = Vt + ((size_t)bn * HDIM + d0 + dr) * SEQ + s20 + ch;
        *(int4*)dp       = *(int4*)&tmp[0];
        *(int4*)(dp + 8) = *(int4*)&tmp[8];
    }
}

// ---------------------------------------------------------------------------
// attn9: 32 q-rows per wave (2 row-tiles), QBLK=128, kv-SPLIT flash attention.
// 512 blocks = 32 heads x 8 pairs x 2 kv-splits; phases (15-pp,sp)+(pp,sp) ->
// exactly 17 KVBLK=64 steps per block. K and V both double-buffered via
// global_load_lds (linear dest, XOR-pre-swizzled src); ONE barrier per step,
// no mid-step waits, no cross-wave V race. Swapped QK^T in-register softmax
// (lane owns full P-row), in-reg P redistribution, l via P*ones MFMA
// (C-layout, matches partial write). Partials: bf16 O + (m,l) -> combine.
// ---------------------------------------------------------------------------
__global__ __launch_bounds__(256) void attn9(
    const short* __restrict__ Qh, const short* __restrict__ Kh,
    const short* __restrict__ Vt, short* __restrict__ Opart,
    float2* __restrict__ ML)
{
    __shared__ __align__(16) short Kls[2][64 * 128];   // 32 KB
    __shared__ __align__(16) short Vls[2][128 * 64];   // 32 KB

    const int t = threadIdx.x, lane = t & 63, w = t >> 6;
    const int lr = lane & 15, lg = lane >> 4;

    const int g   = blockIdx.x;       // 0..511
    const int bn  = g & 31;           // head; bn%8 == g%8 (XCD affinity)
    const int cfg = g >> 5;           // 0..15
    const int pp  = cfg & 7;
    const int sp  = cfg >> 3;         // kv split 0/1

    const short* Qb = Qh + (size_t)bn * SEQ * HDIM;
    const short* Kb = Kh + (size_t)bn * SEQ * HDIM;
    const short* Vb = Vt + (size_t)bn * HDIM * SEQ;

    auto stageK = [&](int buf, int k0) {
        #pragma unroll
        for (int i = 0; i < 4; ++i) {
            const int q = w * 4 + i;
            const int rowK = q * 4 + (lane >> 4);
            const short* src = Kb + (size_t)(k0 + rowK) * 128 + (((lane & 15) ^ (rowK & 7)) * 8);
            __builtin_amdgcn_global_load_lds(
                (const __attribute__((address_space(1))) unsigned int*)src,
                (__attribute__((address_space(3))) unsigned int*)&Kls[buf][q * 512 + lane * 8],
                16, 0, 0);
        }
    };
    auto stageV = [&](int buf, int k0) {
        #pragma unroll
        for (int i = 0; i < 4; ++i) {
            const int q = w * 4 + i;
            const int d = q * 8 + (lane >> 3);
            const short* src = Vb + (size_t)d * SEQ + k0 + (((lane & 7) ^ (d & 7)) * 8);
            __builtin_amdgcn_global_load_lds(
                (const __attribute__((address_space(1))) unsigned int*)src,
                (__attribute__((address_space(3))) unsigned int*)&Vls[buf][q * 512 + lane * 8],
                16, 0, 0);
        }
    };

    const int sw = lr & 7;
    const bool hi16 = (lg & 1);

    bfrag ones;
    #pragma unroll
    for (int k = 0; k < 8; ++k) ones[k] = (short)0x3F80;   // bf16 1.0

    #pragma unroll 1
    for (int phase = 0; phase < 2; ++phase) {
        const int tile = phase ? pp : (15 - pp);
        const int nst  = tile + 1;              // steps in this phase
        const int base = sp * 64 * nst;         // kv window start
        const int q0   = tile * 128 + w * 32;   // wave's first q row

        bfrag qf[2][4];
        #pragma unroll
        for (int rt = 0; rt < 2; ++rt)
            #pragma unroll
            for (int c = 0; c < 4; ++c)
                qf[rt][c] = *(const bfrag*)(Qb + (size_t)(q0 + rt * 16 + lr) * 128 + c * 32 + lg * 8);

        float mcs[2] = {-1.0e30f, -1.0e30f};
        f32x4 l4[2] = {z4(), z4()};
        f32x4 o[2][8];
        #pragma unroll
        for (int rt = 0; rt < 2; ++rt)
            #pragma unroll
            for (int dt = 0; dt < 8; ++dt) o[rt][dt] = z4();

        stageV(0, base);
        stageK(0, base);
        __syncthreads();

        for (int s = 0; s < nst; ++s) {
            const int cur = s & 1;
            const int k0 = base + s * 64;
            if (s + 1 < nst) { stageV(cur ^ 1, k0 + 64); stageK(cur ^ 1, k0 + 64); }

            int ktend = ((q0 + 31 - k0) >> 4) + 1;
            ktend = ktend < 0 ? 0 : (ktend > 4 ? 4 : ktend);

            if (ktend > 0) {
                // ---- swapped QK^T: sA[rt][kt][j] = S^T[k0+kt*16+lg*4+j][q0+rt*16+lr]
                f32x4 sA[2][4];
                #pragma unroll
                for (int rt = 0; rt < 2; ++rt)
                    #pragma unroll
                    for (int kt = 0; kt < 4; ++kt) sA[rt][kt] = z4();
                __builtin_amdgcn_s_setprio(1);
                for (int kt = 0; kt < ktend; ++kt) {
                    const char* kbase = (const char*)&Kls[cur][0] + (kt * 16 + lr) * 256;
                    #pragma unroll
                    for (int c = 0; c < 4; ++c) {
                        bfrag kb = *(const bfrag*)(kbase + (((c * 4 + lg) ^ sw) * 16));
                        sA[0][kt] = mfma16(kb, qf[0][c], sA[0][kt]);
                        sA[1][kt] = mfma16(kb, qf[1][c], sA[1][kt]);
                    }
                }
                __builtin_amdgcn_s_setprio(0);

                // ---- causal mask (near-diagonal steps)
                if (k0 + 63 > q0) {
                    #pragma unroll
                    for (int rt = 0; rt < 2; ++rt)
                        #pragma unroll
                        for (int kt = 0; kt < 4; ++kt)
                            #pragma unroll
                            for (int j = 0; j < 4; ++j)
                                if (k0 + kt * 16 + lg * 4 + j > q0 + rt * 16 + lr)
                                    sA[rt][kt][j] = -3.0e38f;
                }

                // ---- row max per rt (lane-local row) + T13 defer-rescale
                float pmx[2];
                #pragma unroll
                for (int rt = 0; rt < 2; ++rt) {
                    float mx = fmaxf(fmaxf(sA[rt][0][0], sA[rt][0][1]),
                                     fmaxf(sA[rt][0][2], sA[rt][0][3]));
                    #pragma unroll
                    for (int kt = 1; kt < 4; ++kt)
                        mx = fmaxf(mx, fmaxf(fmaxf(sA[rt][kt][0], sA[rt][kt][1]),
                                             fmaxf(sA[rt][kt][2], sA[rt][kt][3])));
                    mx = fmaxf(mx, __shfl_xor(mx, 16));
                    mx = fmaxf(mx, __shfl_xor(mx, 32));
                    pmx[rt] = mx * CS;
                }
                bool need = (pmx[0] > mcs[0] + 8.0f) || (pmx[1] > mcs[1] + 8.0f);
                if (__any(need ? 1 : 0)) {
                    #pragma unroll
                    for (int rt = 0; rt < 2; ++rt) {
                        float nm = fmaxf(mcs[rt], pmx[rt]);
                        float al = exp2f(mcs[rt] - nm);
                        mcs[rt] = nm;
                        float alj[4];
                        #pragma unroll
                        for (int j = 0; j < 4; ++j) alj[j] = __shfl(al, lg * 4 + j);
                        #pragma unroll
                        for (int j = 0; j < 4; ++j) l4[rt][j] *= alj[j];
                        #pragma unroll
                        for (int dt = 0; dt < 8; ++dt)
                            #pragma unroll
                            for (int j = 0; j < 4; ++j) o[rt][dt][j] *= alj[j];
                    }
                }

                // ---- P = exp2(S*CS - mcs), in-reg redistribution per rt
                bfrag pa0[2], pa1[2];
                #pragma unroll
                for (int rt = 0; rt < 2; ++rt) {
                    float p[4][4];
                    #pragma unroll
                    for (int kt = 0; kt < 4; ++kt)
                        #pragma unroll
                        for (int j = 0; j < 4; ++j)
                            p[kt][j] = exp2f(sA[rt][kt][j] * CS - mcs[rt]);
                    redist(p, hi16, pa0[rt], pa1[rt]);
                }

                // ---- l via P*ones MFMA (C-layout accumulate)
                #pragma unroll
                for (int rt = 0; rt < 2; ++rt)
                    l4[rt] = mfma16(pa0[rt], ones, mfma16(pa1[rt], ones, l4[rt]));

                // ---- PV from Vls[cur] (resident since prev barrier)
                __builtin_amdgcn_s_setprio(1);
                #pragma unroll
                for (int dt = 0; dt < 8; ++dt) {
                    const char* vbase = (const char*)&Vls[cur][0] + (dt * 16 + lr) * 128;
                    bfrag vb0 = *(const bfrag*)(vbase + ((lg ^ sw) * 16));
                    bfrag vb1 = *(const bfrag*)(vbase + (((4 + lg) ^ sw) * 16));
                    #pragma unroll
                    for (int rt = 0; rt < 2; ++rt) {
                        o[rt][dt] = mfma16(pa0[rt], vb0, o[rt][dt]);
                        o[rt][dt] = mfma16(pa1[rt], vb1, o[rt][dt]);
                    }
                }
                __builtin_amdgcn_s_setprio(0);
            }

            __syncthreads();   // drains next-step loads; frees cur for rewrite
        }

        // ---- partial epilogue: bf16 O + (m,l) per row
        short* OpW = Opart + ((size_t)sp * NROWS + (size_t)bn * SEQ) * 128;
        float2* MLW = ML + (size_t)sp * NROWS + (size_t)bn * SEQ;
        #pragma unroll
        for (int rt = 0; rt < 2; ++rt) {
            float m4[4];
            #pragma unroll
            for (int j = 0; j < 4; ++j) m4[j] = __shfl(mcs[rt], lg * 4 + j);
            #pragma unroll
            for (int j = 0; j < 4; ++j) {
                int row = q0 + rt * 16 + lg * 4 + j;
                #pragma unroll
                for (int dt = 0; dt < 8; ++dt)
                    OpW[(size_t)row * 128 + dt * 16 + lr] = f2bf(o[rt][dt][j]);
                if (lr == 0)
                    MLW[row] = make_float2(m4[j], l4[rt][j]);
            }
        }
    }
}

// ---------------------------------------------------------------------------
// combine: merge the two kv-split partials, normalize, permuted scatter to Yb.
// ---------------------------------------------------------------------------
__global__ __launch_bounds__(256) void combine(
    const short* __restrict__ Op, const float2* __restrict__ ML,
    short* __restrict__ Y)
{
    const int idx = blockIdx.x * 256 + threadIdx.x;   // 1,048,576 threads
    const int row = idx >> 4;                          // 0..65535
    const int c0  = (idx & 15) * 8;

    float2 ml0 = ML[row];
    float2 ml1 = ML[NROWS + row];
    float m  = fmaxf(ml0.x, ml1.x);
    float w0 = exp2f(ml0.x - m), w1 = exp2f(ml1.x - m);
    float inv = 1.0f / (ml0.y * w0 + ml1.y * w1);

    const short* p0 = Op + (size_t)row * 128 + c0;
    const short* p1 = Op + (size_t)NROWS * 128 + (size_t)row * 128 + c0;
    s16x4 a0 = *(const s16x4*)p0, a1 = *(const s16x4*)(p0 + 4);
    s16x4 b0 = *(const s16x4*)p1, b1 = *(const s16x4*)(p1 + 4);

    union { s16x4 v[2]; int4 u; } outv;
    #pragma unroll
    for (int i = 0; i < 4; ++i)
        outv.v[0][i] = f2bf((bf2f(a0[i]) * w0 + bf2f(b0[i]) * w1) * inv);
    #pragma unroll
    for (int i = 0; i < 4; ++i)
        outv.v[1][i] = f2bf((bf2f(a1[i]) * w0 + bf2f(b1[i]) * w1) * inv);

    const int bn = row >> 11, q = row & 2047;
    const int b = bn >> 3, n = bn & 7;
    size_t yrow = (size_t)b * SEQ + n * 256 + (q >> 3);
    short* yp = Y + yrow * YN + (q & 7) * 128 + c0;
    *(int4*)yp = outv.u;
}

// ---------------------------------------------------------------------------
// GEMM2: out[8192][128] (f32) = Yb[8192][1024](bf16) @ proj, B as projT[h][k].
// ---------------------------------------------------------------------------
__global__ __launch_bounds__(128) void gemm_out(
    const short* __restrict__ Yb, const short* __restrict__ projT, float* __restrict__ out)
{
    const int t = threadIdx.x, lane = t & 63, w = t >> 6;   // w in 0..1
    const int lr = lane & 15, lg = lane >> 4;
    const int m0 = blockIdx.x * 16;
    const int n0 = w * 64;

    f32x4 acc[4];
    #pragma unroll
    for (int j = 0; j < 4; ++j) acc[j] = z4();

    for (int c = 0; c < 32; ++c) {
        bfrag a = *(const bfrag*)(Yb + (size_t)(m0 + lr) * YN + c * 32 + lg * 8);
        #pragma unroll
        for (int nt = 0; nt < 4; ++nt) {
            bfrag bb = *(const bfrag*)(projT + (size_t)(n0 + nt * 16 + lr) * YN + c * 32 + lg * 8);
            acc[nt] = mfma16(a, bb, acc[nt]);
        }
    }
    #pragma unroll
    for (int nt = 0; nt < 4; ++nt)
        #pragma unroll
        for (int j = 0; j < 4; ++j)
            out[(size_t)(m0 + lg * 4 + j) * HDIM + n0 + nt * 16 + lr] = acc[nt][j];
}

// ---------------------------------------------------------------------------
extern "C" void kernel_launch(void* const* d_in, const int* in_sizes, int n_in,
                              void* d_out, int out_size, void* d_ws, size_t ws_size,
                              hipStream_t stream)
{
    const float* x    = (const float*)d_in[0];  // [4,2048,128]
    const float* qkv  = (const float*)d_in[1];  // [128,3072]
    const float* proj = (const float*)d_in[2];  // [1024,128]
    float* out = (float*)d_out;                 // [8192,128]

    const size_t HEADSZ = (size_t)32 * SEQ * HDIM;        // 8,388,608 elements

    short* XB    = (short*)d_ws;                          // 2 MB
    short* qkvT  = XB    + (size_t)MROWS * HDIM;
    short* projT = qkvT  + (size_t)QKVN * HDIM;
    short* Qh    = projT + (size_t)HDIM * YN;             // 16 MB
    short* Kh    = Qh    + HEADSZ;                        // 16 MB
    short* Vh    = Kh    + HEADSZ;                        // 16 MB
    short* Vtb   = Vh    + HEADSZ;                        // 16 MB
    short* Yb    = Vtb   + HEADSZ;                        // 16 MB
    short* Opart = Yb    + HEADSZ;                        // 2 x 16 MB bf16 partials
    float2* ML   = (float2*)(Opart + 2 * HEADSZ);         // 2 x 65536 float2 (1 MB)
    // total ~122 MB

    conv_x    <<<MROWS * HDIM / 1024, 256, 0, stream>>>(x, XB);
    conv_qkvT <<<QKVN * HDIM / 256,  256, 0, stream>>>(qkv, qkvT);
    conv_projT<<<HDIM * YN / 256,    256, 0, stream>>>(proj, projT);

    gemm_qkv<<<dim3(MROWS / 128, QKVN / 128), 256, 0, stream>>>(XB, qkvT, Qh, Kh, Vh);
    transp_v<<<dim3(SEQ / 64, HDIM / 64, 32), 256, 0, stream>>>(Vh, Vtb);
    attn9   <<<512, 256, 0, stream>>>(Qh, Kh, Vtb, Opart, ML);
    combine <<<NROWS * 16 / 256, 256, 0, stream>>>(Opart, ML, Yb);
    gemm_out<<<MROWS / 16, 128, 0, stream>>>(Yb, projT, out);
}

// Round 13
// 146.601 us; speedup vs baseline: 1.3629x; 1.3629x over previous
//
#include <hip/hip_runtime.h>
#include <math.h>

// Problem constants
#define BATCH 4
#define SEQ   2048
#define HDIM  128
#define NHEAD 8
#define MROWS (BATCH*SEQ)    // 8192
#define QKVN  (3*NHEAD*HDIM) // 3072
#define YN    (NHEAD*HDIM)   // 1024

#define CS 0.12751744f   // (1/sqrt(128)) * log2(e)

using bfrag = __attribute__((ext_vector_type(8))) short;  // 8 bf16 (4 VGPRs)
using f32x4 = __attribute__((ext_vector_type(4))) float;
using s16x4 = __attribute__((ext_vector_type(4))) short;

__device__ __forceinline__ f32x4 mfma16(bfrag a, bfrag b, f32x4 c) {
    return __builtin_amdgcn_mfma_f32_16x16x32_bf16(a, b, c, 0, 0, 0);
}
__device__ __forceinline__ short f2bf(float f) {
    union { float f; unsigned u; } v; v.f = f;
    unsigned r = v.u + 0x7FFFu + ((v.u >> 16) & 1u);  // RNE
    return (short)(r >> 16);
}
__device__ __forceinline__ unsigned cvtpk(float lo, float hi) {
    unsigned r;
    asm("v_cvt_pk_bf16_f32 %0, %1, %2" : "=v"(r) : "v"(lo), "v"(hi));
    return r;
}
__device__ __forceinline__ void perm32swap(unsigned &x, unsigned &y) {
    asm volatile("v_permlane32_swap_b32 %0, %1" : "+v"(x), "+v"(y));
}
__device__ __forceinline__ f32x4 z4() { f32x4 z; z[0]=0.f; z[1]=0.f; z[2]=0.f; z[3]=0.f; return z; }

// In-register P redistribution (C-layout -> A-frag layout), validated attn8.
__device__ __forceinline__ void redist(const float p[4][4], bool hi16,
                                       bfrag &pa0o, bfrag &pa1o) {
    unsigned pk0[2], pk1[2], pk2[2], pk3[2];
    pk0[0] = cvtpk(p[0][0], p[0][1]); pk0[1] = cvtpk(p[0][2], p[0][3]);
    pk1[0] = cvtpk(p[1][0], p[1][1]); pk1[1] = cvtpk(p[1][2], p[1][3]);
    pk2[0] = cvtpk(p[2][0], p[2][1]); pk2[1] = cvtpk(p[2][2], p[2][3]);
    pk3[0] = cvtpk(p[3][0], p[3][1]); pk3[1] = cvtpk(p[3][2], p[3][3]);
    uint4 w0, w1;
    {
        unsigned A = pk0[0], C = pk1[0];
        perm32swap(A, C);
        unsigned A16 = __shfl_xor((int)A, 16), C16 = __shfl_xor((int)C, 16);
        w0.x = hi16 ? C16 : A;
        w0.z = hi16 ? C   : A16;
        unsigned B = pk0[1], D = pk1[1];
        perm32swap(B, D);
        unsigned B16 = __shfl_xor((int)B, 16), D16 = __shfl_xor((int)D, 16);
        w0.y = hi16 ? D16 : B;
        w0.w = hi16 ? D   : B16;
    }
    {
        unsigned E = pk2[0], G = pk3[0];
        perm32swap(E, G);
        unsigned E16 = __shfl_xor((int)E, 16), G16 = __shfl_xor((int)G, 16);
        w1.x = hi16 ? G16 : E;
        w1.z = hi16 ? G   : E16;
        unsigned F = pk2[1], H = pk3[1];
        perm32swap(F, H);
        unsigned F16 = __shfl_xor((int)F, 16), H16 = __shfl_xor((int)H, 16);
        w1.y = hi16 ? H16 : F;
        w1.w = hi16 ? H   : F16;
    }
    union { uint4 u; bfrag f; } cv0, cv1;
    cv0.u = w0; cv1.u = w1;
    pa0o = cv0.f; pa1o = cv1.f;
}

// ---------------------------------------------------------------------------
// Converters
// ---------------------------------------------------------------------------
__global__ __launch_bounds__(256) void conv_x(const float* __restrict__ x, short* __restrict__ XB) {
    int i = (blockIdx.x * 256 + threadIdx.x) * 4;
    float4 v = *(const float4*)(x + i);
    s16x4 o; o[0] = f2bf(v.x); o[1] = f2bf(v.y); o[2] = f2bf(v.z); o[3] = f2bf(v.w);
    *(s16x4*)(XB + i) = o;
}
__global__ __launch_bounds__(256) void conv_qkvT(const float* __restrict__ q, short* __restrict__ qT) {
    int t = blockIdx.x * 256 + threadIdx.x;         // 3072*128
    int n = t >> 7, k = t & 127;
    qT[t] = f2bf(q[(size_t)k * QKVN + n]);
}
__global__ __launch_bounds__(256) void conv_projT(const float* __restrict__ p, short* __restrict__ pT) {
    int t = blockIdx.x * 256 + threadIdx.x;         // 128*1024
    int h = t >> 10, r = t & 1023;
    pT[t] = f2bf(p[(size_t)r * HDIM + h]);
}

// ---------------------------------------------------------------------------
// GEMM1: x @ qkv scattered into per-head Qh/Kh/Vh[(b*8+n)*2048 + s2][h]
// ---------------------------------------------------------------------------
__global__ __launch_bounds__(256) void gemm_qkv(
    const short* __restrict__ XB, const short* __restrict__ qkvT,
    short* __restrict__ Qh, short* __restrict__ Kh, short* __restrict__ Vh)
{
    const int t = threadIdx.x, lane = t & 63, w = t >> 6;
    const int lr = lane & 15, lg = lane >> 4;
    const int m0 = blockIdx.x * 128 + (w >> 1) * 64;
    const int n0 = blockIdx.y * 128 + (w & 1) * 64;

    f32x4 acc[4][4];
    #pragma unroll
    for (int i = 0; i < 4; ++i)
        #pragma unroll
        for (int j = 0; j < 4; ++j) acc[i][j] = z4();

    #pragma unroll
    for (int c = 0; c < 4; ++c) {
        bfrag a[4], bb[4];
        #pragma unroll
        for (int rt = 0; rt < 4; ++rt)
            a[rt] = *(const bfrag*)(XB + (size_t)(m0 + rt * 16 + lr) * 128 + c * 32 + lg * 8);
        #pragma unroll
        for (int nt = 0; nt < 4; ++nt)
            bb[nt] = *(const bfrag*)(qkvT + (size_t)(n0 + nt * 16 + lr) * 128 + c * 32 + lg * 8);
        #pragma unroll
        for (int rt = 0; rt < 4; ++rt)
            #pragma unroll
            for (int nt = 0; nt < 4; ++nt)
                acc[rt][nt] = mfma16(a[rt], bb[nt], acc[rt][nt]);
    }

    const int part = blockIdx.y >> 3, c8 = blockIdx.y & 7;
    short* dst = (part == 0) ? Qh : ((part == 1) ? Kh : Vh);
    #pragma unroll
    for (int rt = 0; rt < 4; ++rt)
        #pragma unroll
        for (int j = 0; j < 4; ++j) {
            int r = m0 + rt * 16 + lg * 4 + j;
            int b = r >> 11, sl = r & 2047;
            int n = sl >> 8, s2 = (sl & 255) * 8 + c8;
            size_t rowbase = ((size_t)((b * 8 + n) * 2048 + s2)) * 128;
            #pragma unroll
            for (int nt = 0; nt < 4; ++nt) {
                int h = (w & 1) * 64 + nt * 16 + lr;
                dst[rowbase + h] = f2bf(acc[rt][nt][j]);
            }
        }
}

// ---------------------------------------------------------------------------
// Transpose V per head: Vh[bn][s2][d] -> Vt[bn][d][s2].
// ---------------------------------------------------------------------------
__global__ __launch_bounds__(256) void transp_v(
    const short* __restrict__ Vh, short* __restrict__ Vt)
{
    __shared__ short Ls[64][72];
    const int bn = blockIdx.z, s20 = blockIdx.x * 64, d0 = blockIdx.y * 64;
    const int t = threadIdx.x;
    const short* src = Vh + ((size_t)bn * SEQ + s20) * 128 + d0;
    {
        int r = t >> 2, ch = (t & 3) * 16;
        *(int4*)&Ls[r][ch]     = *(const int4*)(src + (size_t)r * 128 + ch);
        *(int4*)&Ls[r][ch + 8] = *(const int4*)(src + (size_t)r * 128 + ch + 8);
    }
    __syncthreads();
    {
        int dr = t >> 2, ch = (t & 3) * 16;
        short tmp[16];
        #pragma unroll
        for (int i = 0; i < 16; ++i) tmp[i] = Ls[ch + i][dr];
        short* dp = Vt + ((size_t)bn * HDIM + d0 + dr) * SEQ + s20 + ch;
        *(int4*)dp       = *(int4*)&tmp[0];
        *(int4*)(dp + 8) = *(int4*)&tmp[8];
    }
}

// ---------------------------------------------------------------------------
// attn10: attn8's work decomposition (16 q-rows/wave, QBLK=64, tile-pairing
// (pp, 31-pp) -> 33 uniform steps, XCD affinity) + race-free dbuf sync
// (K AND V double-buffered; stage s+1 at top of step s; ONE barrier/step;
// no mid-step vmcnt; no cross-wave V race) + STATIC kt loop (rule #20:
// runtime-bounded loops with sA[kt] indexing go to scratch; use unrolled
// kt 0..3 with a wave-uniform predicate). LDS 64 KB = 2 blocks/CU = the
// 512-block grid's capacity -> flat occupancy.
// ---------------------------------------------------------------------------
__global__ __launch_bounds__(256) void attn10(
    const short* __restrict__ Qh, const short* __restrict__ Kh,
    const short* __restrict__ Vt, short* __restrict__ Y)
{
    __shared__ __align__(16) short Kls[2][64 * 128];   // 32 KB
    __shared__ __align__(16) short Vls[2][128 * 64];   // 32 KB

    const int t = threadIdx.x, lane = t & 63, w = t >> 6;
    const int lr = lane & 15, lg = lane >> 4;

    const int g  = blockIdx.x;        // 0..511
    const int bn = g & 31;            // head id; bn%8 == g%8 (XCD affinity)
    const int pp = g >> 5;            // pair id 0..15 -> tiles (pp, 31-pp)
    const int b  = bn >> 3, n = bn & 7;

    const short* Qb = Qh + (size_t)bn * SEQ * HDIM;
    const short* Kb = Kh + (size_t)bn * SEQ * HDIM;
    const short* Vb = Vt + (size_t)bn * HDIM * SEQ;

    // async staging: linear LDS dest, XOR-involution pre-swizzled global src
    auto stageK = [&](int buf, int k0) {
        #pragma unroll
        for (int i = 0; i < 4; ++i) {
            const int q = w * 4 + i;
            const int rowK = q * 4 + (lane >> 4);
            const short* src = Kb + (size_t)(k0 + rowK) * 128 + (((lane & 15) ^ (rowK & 7)) * 8);
            __builtin_amdgcn_global_load_lds(
                (const __attribute__((address_space(1))) unsigned int*)src,
                (__attribute__((address_space(3))) unsigned int*)&Kls[buf][q * 512 + lane * 8],
                16, 0, 0);
        }
    };
    auto stageV = [&](int buf, int k0) {
        #pragma unroll
        for (int i = 0; i < 4; ++i) {
            const int q = w * 4 + i;
            const int d = q * 8 + (lane >> 3);
            const short* src = Vb + (size_t)d * SEQ + k0 + (((lane & 7) ^ (d & 7)) * 8);
            __builtin_amdgcn_global_load_lds(
                (const __attribute__((address_space(1))) unsigned int*)src,
                (__attribute__((address_space(3))) unsigned int*)&Vls[buf][q * 512 + lane * 8],
                16, 0, 0);
        }
    };

    const int sw = lr & 7;
    const bool hi16 = (lg & 1);

    #pragma unroll 1
    for (int phase = 0; phase < 2; ++phase) {
        const int tile = phase ? pp : (31 - pp);    // long tile first
        const int q0 = tile * 64 + w * 16;

        bfrag qf[4];
        #pragma unroll
        for (int c = 0; c < 4; ++c)
            qf[c] = *(const bfrag*)(Qb + (size_t)(q0 + lr) * 128 + c * 32 + lg * 8);

        float mcs = -1.0e30f, l = 0.f;              // per-lane: q = q0 + lr
        f32x4 o[8];
        #pragma unroll
        for (int dt = 0; dt < 8; ++dt) o[dt] = z4();

        stageV(0, 0);
        stageK(0, 0);
        __syncthreads();   // buffer 0 staged

        for (int s = 0; s <= tile; ++s) {
            const int cur = s & 1;
            const int k0 = s * 64;
            if (s < tile) { stageV(cur ^ 1, k0 + 64); stageK(cur ^ 1, k0 + 64); }

            // ---- swapped QK^T: sA[kt][j] = S^T[k = kt*16+lg*4+j][q = q0+lr]
            // STATIC unrolled kt loop; wave-uniform predicate for diagonal skip.
            f32x4 sA[4];
            #pragma unroll
            for (int kt = 0; kt < 4; ++kt) sA[kt] = z4();
            const int ktend = (s == tile) ? (w + 1) : 4;
            __builtin_amdgcn_s_setprio(1);
            #pragma unroll
            for (int kt = 0; kt < 4; ++kt) {
                if (kt < ktend) {   // wave-uniform
                    const char* kbase = (const char*)&Kls[cur][0] + (kt * 16 + lr) * 256;
                    #pragma unroll
                    for (int c = 0; c < 4; ++c) {
                        bfrag kb = *(const bfrag*)(kbase + (((c * 4 + lg) ^ sw) * 16));
                        sA[kt] = mfma16(kb, qf[c], sA[kt]);   // swapped operands
                    }
                }
            }
            __builtin_amdgcn_s_setprio(0);

            // ---- causal mask (diagonal step only): k_local > q_local
            if (s == tile) {
                #pragma unroll
                for (int kt = 0; kt < 4; ++kt)
                    #pragma unroll
                    for (int j = 0; j < 4; ++j)
                        if (kt * 16 + lg * 4 + j > w * 16 + lr)
                            sA[kt][j] = -3.0e38f;
            }

            // ---- row max: in-lane tree + 2 cross-lg shuffles (full k-row)
            float mx = fmaxf(fmaxf(sA[0][0], sA[0][1]), fmaxf(sA[0][2], sA[0][3]));
            #pragma unroll
            for (int kt = 1; kt < 4; ++kt)
                mx = fmaxf(mx, fmaxf(fmaxf(sA[kt][0], sA[kt][1]),
                                     fmaxf(sA[kt][2], sA[kt][3])));
            mx = fmaxf(mx, __shfl_xor(mx, 16));
            mx = fmaxf(mx, __shfl_xor(mx, 32));
            const float pmx = mx * CS;

            // ---- T13 defer-rescale (rare)
            if (__any((pmx > mcs + 8.0f) ? 1 : 0)) {
                float nm = fmaxf(mcs, pmx);
                float al = exp2f(mcs - nm);
                mcs = nm;
                l *= al;
                float alj[4];
                #pragma unroll
                for (int j = 0; j < 4; ++j) alj[j] = __shfl(al, lg * 4 + j);
                #pragma unroll
                for (int dt = 0; dt < 8; ++dt)
                    #pragma unroll
                    for (int j = 0; j < 4; ++j) o[dt][j] *= alj[j];
            }

            // ---- P = exp2(S*CS - mcs) (lane-local row) + l-sum
            float p[4][4];
            float ls = 0.f;
            #pragma unroll
            for (int kt = 0; kt < 4; ++kt)
                #pragma unroll
                for (int j = 0; j < 4; ++j) {
                    p[kt][j] = exp2f(sA[kt][j] * CS - mcs);
                    ls += p[kt][j];
                }
            ls += __shfl_xor(ls, 16);
            ls += __shfl_xor(ls, 32);
            l += ls;

            // ---- in-register P redistribution
            bfrag pa0, pa1;
            redist(p, hi16, pa0, pa1);

            // ---- PV from Vls[cur] (staged since prev barrier; race-free)
            __builtin_amdgcn_s_setprio(1);
            #pragma unroll
            for (int dt = 0; dt < 8; ++dt) {
                const char* vbase = (const char*)&Vls[cur][0] + (dt * 16 + lr) * 128;
                bfrag vb0 = *(const bfrag*)(vbase + ((lg ^ sw) * 16));
                bfrag vb1 = *(const bfrag*)(vbase + (((4 + lg) ^ sw) * 16));
                o[dt] = mfma16(pa0, vb0, o[dt]);
                o[dt] = mfma16(pa1, vb1, o[dt]);
            }
            __builtin_amdgcn_s_setprio(0);

            __syncthreads();   // drains s+1 loads (issued a full step ago ~free)
        }

        // ---- epilogue: l (q=lr layout) -> per-j inverses, scatter bf16 to Y
        float inv[4];
        #pragma unroll
        for (int j = 0; j < 4; ++j) inv[j] = 1.0f / __shfl(l, lg * 4 + j);
        #pragma unroll
        for (int j = 0; j < 4; ++j) {
            int s2 = q0 + lg * 4 + j;
            size_t yrow = (size_t)b * SEQ + n * 256 + (s2 >> 3);
            short* yp = Y + yrow * YN + (s2 & 7) * 128 + lr;
            #pragma unroll
            for (int dt = 0; dt < 8; ++dt)
                yp[dt * 16] = f2bf(o[dt][j] * inv[j]);
        }
    }
}

// ---------------------------------------------------------------------------
// GEMM2: out[8192][128] (f32) = Yb[8192][1024](bf16) @ proj, B as projT[h][k].
// ---------------------------------------------------------------------------
__global__ __launch_bounds__(128) void gemm_out(
    const short* __restrict__ Yb, const short* __restrict__ projT, float* __restrict__ out)
{
    const int t = threadIdx.x, lane = t & 63, w = t >> 6;   // w in 0..1
    const int lr = lane & 15, lg = lane >> 4;
    const int m0 = blockIdx.x * 16;
    const int n0 = w * 64;

    f32x4 acc[4];
    #pragma unroll
    for (int j = 0; j < 4; ++j) acc[j] = z4();

    for (int c = 0; c < 32; ++c) {
        bfrag a = *(const bfrag*)(Yb + (size_t)(m0 + lr) * YN + c * 32 + lg * 8);
        #pragma unroll
        for (int nt = 0; nt < 4; ++nt) {
            bfrag bb = *(const bfrag*)(projT + (size_t)(n0 + nt * 16 + lr) * YN + c * 32 + lg * 8);
            acc[nt] = mfma16(a, bb, acc[nt]);
        }
    }
    #pragma unroll
    for (int nt = 0; nt < 4; ++nt)
        #pragma unroll
        for (int j = 0; j < 4; ++j)
            out[(size_t)(m0 + lg * 4 + j) * HDIM + n0 + nt * 16 + lr] = acc[nt][j];
}

// ---------------------------------------------------------------------------
extern "C" void kernel_launch(void* const* d_in, const int* in_sizes, int n_in,
                              void* d_out, int out_size, void* d_ws, size_t ws_size,
                              hipStream_t stream)
{
    const float* x    = (const float*)d_in[0];  // [4,2048,128]
    const float* qkv  = (const float*)d_in[1];  // [128,3072]
    const float* proj = (const float*)d_in[2];  // [1024,128]
    float* out = (float*)d_out;                 // [8192,128]

    const size_t HEADSZ = (size_t)32 * SEQ * HDIM;        // 8,388,608 elements

    short* XB    = (short*)d_ws;                          // 2 MB
    short* qkvT  = XB    + (size_t)MROWS * HDIM;
    short* projT = qkvT  + (size_t)QKVN * HDIM;
    short* Qh    = projT + (size_t)HDIM * YN;             // 16 MB
    short* Kh    = Qh    + HEADSZ;                        // 16 MB
    short* Vh    = Kh    + HEADSZ;                        // 16 MB
    short* Vtb   = Vh    + HEADSZ;                        // 16 MB
    short* Yb    = Vtb   + HEADSZ;                        // 16 MB  (~85 MB total)

    conv_x    <<<MROWS * HDIM / 1024, 256, 0, stream>>>(x, XB);
    conv_qkvT <<<QKVN * HDIM / 256,  256, 0, stream>>>(qkv, qkvT);
    conv_projT<<<HDIM * YN / 256,    256, 0, stream>>>(proj, projT);

    gemm_qkv<<<dim3(MROWS / 128, QKVN / 128), 256, 0, stream>>>(XB, qkvT, Qh, Kh, Vh);
    transp_v<<<dim3(SEQ / 64, HDIM / 64, 32), 256, 0, stream>>>(Vh, Vtb);
    attn10  <<<512, 256, 0, stream>>>(Qh, Kh, Vtb, Yb);
    gemm_out<<<MROWS / 16, 128, 0, stream>>>(Yb, projT, out);
}